// Round 12
// baseline (80.773 us; speedup 1.0000x reference)
//
#include <hip/hip_runtime.h>

typedef __attribute__((ext_vector_type(8))) short short8;
typedef __attribute__((ext_vector_type(4))) float f32x4;

constexpr int Bn = 4, Cn = 192, Tn = 2048, Hn = 4, HD = 48;
constexpr float LOG2E = 1.4426950408889634f;
constexpr float QK_SCALE2 = 0.14433756729740643f * 1.4426950408889634f;  // rsqrt(48)*log2e
constexpr float NEG100_LOG2 = -100.0f * 1.4426950408889634f;

__device__ inline unsigned short f2bf(float f) {
  unsigned int u = __builtin_bit_cast(unsigned int, f);
  return (unsigned short)((u + 0x7FFFu + ((u >> 16) & 1u)) >> 16);
}
__device__ inline float bf2f(unsigned short h) {
  unsigned int u = ((unsigned int)h) << 16;
  return __builtin_bit_cast(float, u);
}
__device__ inline f32x4 mfma16(short8 a, short8 b, f32x4 c) {
  return __builtin_amdgcn_mfma_f32_16x16x32_bf16(a, b, c, 0, 0, 0);
}
__device__ inline unsigned int cvtpk(float lo, float hi) {
  unsigned int r;
  asm("v_cvt_pk_bf16_f32 %0, %1, %2" : "=v"(r) : "v"(lo), "v"(hi));
  return r;
}

// ------------------------------------------------- transpose x + weights + decay
// z<Bn : x[b][c][t] f32 -> XT[b][t][c] bf16 (b=z)
// z==Bn: W[k][n] f32 -> WT[j][n][k] bf16 (j=0..3: Wq,Wk,Wc,Wp), 144 tile-jobs
// z==Bn+1: decay from x (f32): g[b][h][t] = 0.25*sum_f (f+1)*sigmoid(x_t.Wd+bd)
__global__ __launch_bounds__(256) void transpose_xw(const float* __restrict__ x,
                                                    const float* __restrict__ Wq,
                                                    const float* __restrict__ Wk,
                                                    const float* __restrict__ Wc,
                                                    const float* __restrict__ Wp,
                                                    const float* __restrict__ Wd,
                                                    const float* __restrict__ bd,
                                                    short* __restrict__ xt,
                                                    short* __restrict__ WT,
                                                    float* __restrict__ gout) {
  __shared__ short tile[32][40];
  int tid = threadIdx.x;
  int row = tid >> 3, q = tid & 7;
  int z = blockIdx.z;
  if (z < Bn) {
    int t0 = blockIdx.x * 32, c0 = blockIdx.y * 32, b = z;
    float4 v = *(const float4*)(x + ((size_t)(b * Cn + c0 + row)) * Tn + t0 + q * 4);
    tile[row][q * 4 + 0] = (short)f2bf(v.x);
    tile[row][q * 4 + 1] = (short)f2bf(v.y);
    tile[row][q * 4 + 2] = (short)f2bf(v.z);
    tile[row][q * 4 + 3] = (short)f2bf(v.w);
    __syncthreads();
    ushort4 pk;
    pk.x = (unsigned short)tile[q * 4 + 0][row];
    pk.y = (unsigned short)tile[q * 4 + 1][row];
    pk.z = (unsigned short)tile[q * 4 + 2][row];
    pk.w = (unsigned short)tile[q * 4 + 3][row];
    *(ushort4*)(xt + ((size_t)(b * Tn + t0 + row)) * Cn + c0 + q * 4) = pk;
  } else if (z == Bn) {
    int idx = blockIdx.y * 64 + blockIdx.x;  // 384 slots, need 144
    if (idx >= 144) return;
    int j = idx / 36, t = idx - j * 36;
    int k0 = (t / 6) * 32, n0 = (t % 6) * 32;
    const float* W = (j == 0) ? Wq : (j == 1) ? Wk : (j == 2) ? Wc : Wp;
    float4 v = *(const float4*)(W + (size_t)(k0 + row) * Cn + n0 + q * 4);
    tile[row][q * 4 + 0] = (short)f2bf(v.x);
    tile[row][q * 4 + 1] = (short)f2bf(v.y);
    tile[row][q * 4 + 2] = (short)f2bf(v.z);
    tile[row][q * 4 + 3] = (short)f2bf(v.w);
    __syncthreads();
    ushort4 pk;
    pk.x = (unsigned short)tile[q * 4 + 0][row];
    pk.y = (unsigned short)tile[q * 4 + 1][row];
    pk.z = (unsigned short)tile[q * 4 + 2][row];
    pk.w = (unsigned short)tile[q * 4 + 3][row];
    *(ushort4*)(WT + ((size_t)(j * Cn + n0 + row)) * Cn + k0 + q * 4) = pk;
  } else {
    // decay band: 32 blocks x 256 threads; thread -> one (b,t), all 4 heads
    int idx = blockIdx.y * 64 + blockIdx.x;
    if (idx >= 32) return;
    int bt = idx * 256 + tid;
    int b = bt >> 11, t = bt & 2047;
    const float* xb = x + (size_t)b * Cn * Tn + t;  // x[b][c][t], stride Tn over c
    float d[16];
#pragma unroll
    for (int n = 0; n < 16; ++n) d[n] = bd[n];
#pragma unroll 4
    for (int c = 0; c < Cn; ++c) {
      float xv = xb[(size_t)c * Tn];
      const float* wrow = Wd + c * 16;
#pragma unroll
      for (int n = 0; n < 16; ++n) d[n] = fmaf(xv, wrow[n], d[n]);
    }
#pragma unroll
    for (int h = 0; h < 4; ++h) {
      float gsum = 0.f;
#pragma unroll
      for (int f = 0; f < 4; ++f) {
        float s = 1.f / (1.f + __expf(-d[h * 4 + f]));
        gsum += (float)(f + 1) * s;
      }
      gout[((size_t)(b * 4 + h)) * Tn + t] = 0.25f * gsum;
    }
  }
}

// ---------------------------------------------------------------- fused QKV GEMM
// nt 0..8 over concatenated [WqT;WkT;WcT] rows; Q,K -> t-major bf16; V -> c-major
__global__ __launch_bounds__(256) void gemm_qkv(const short* __restrict__ WT,
                                                const float* __restrict__ bq,
                                                const float* __restrict__ bk,
                                                const float* __restrict__ bc,
                                                const short* __restrict__ Bsrc,
                                                short* __restrict__ Qt,
                                                short* __restrict__ Kt,
                                                short* __restrict__ Vc) {
  constexpr int LDK = 200;
  __shared__ short As[64 * LDK];
  __shared__ short Bs[128 * LDK];
  int tt = blockIdx.x, nt = blockIdx.y, b = blockIdx.z;
  int j = nt / 3;              // 0=Q 1=K 2=V
  int ln0 = (nt - j * 3) * 64; // row within its matrix
  int n0g = nt * 64;           // row in concatenated WT
  int t0 = tt * 128;
  const float* bias = (j == 0) ? bq : (j == 1) ? bk : bc;
  int tid = threadIdx.x, w = tid >> 6, l = tid & 63;
  int g16 = l >> 4, c16 = l & 15;

  for (int idx = tid; idx < 4608; idx += 256) {
    if (idx < 1536) {
      int row = idx / 24, ch = idx % 24;
      *(float4*)(&As[row * LDK + ch * 8]) =
          *(const float4*)(WT + ((size_t)(n0g + row)) * Cn + ch * 8);
    } else {
      int jj = idx - 1536;
      int row = jj / 24, ch = jj % 24;
      *(float4*)(&Bs[row * LDK + ch * 8]) =
          *(const float4*)(Bsrc + ((size_t)(b * Tn + t0 + row)) * Cn + ch * 8);
    }
  }
  __syncthreads();

  f32x4 acc[4][2];
#pragma unroll
  for (int m = 0; m < 4; ++m)
#pragma unroll
    for (int n = 0; n < 2; ++n) acc[m][n] = (f32x4){0.f, 0.f, 0.f, 0.f};

#pragma unroll
  for (int kk = 0; kk < 6; ++kk) {
    short8 af[4], bf[2];
#pragma unroll
    for (int m = 0; m < 4; ++m)
      af[m] = *(const short8*)(&As[(m * 16 + c16) * LDK + kk * 32 + g16 * 8]);
#pragma unroll
    for (int n = 0; n < 2; ++n)
      bf[n] = *(const short8*)(&Bs[(w * 32 + n * 16 + c16) * LDK + kk * 32 + g16 * 8]);
#pragma unroll
    for (int m = 0; m < 4; ++m)
#pragma unroll
      for (int n = 0; n < 2; ++n) acc[m][n] = mfma16(af[m], bf[n], acc[m][n]);
  }

#pragma unroll
  for (int m = 0; m < 4; ++m)
#pragma unroll
    for (int n = 0; n < 2; ++n) {
      int nrow = ln0 + m * 16 + g16 * 4;
      int tcol = t0 + w * 32 + n * 16 + c16;
      if (j == 2) {
#pragma unroll
        for (int r = 0; r < 4; ++r)
          Vc[((size_t)(b * Cn + nrow + r)) * Tn + tcol] =
              (short)f2bf(acc[m][n][r] + bias[nrow + r]);
      } else {
        short* O = j ? Kt : Qt;
        ushort4 pk;
        pk.x = f2bf(acc[m][n][0] + bias[nrow + 0]);
        pk.y = f2bf(acc[m][n][1] + bias[nrow + 1]);
        pk.z = f2bf(acc[m][n][2] + bias[nrow + 2]);
        pk.w = f2bf(acc[m][n][3] + bias[nrow + 3]);
        *(ushort4*)(O + ((size_t)(b * Tn + tcol)) * Cn + nrow) = pk;
      }
    }
}

// ---------------------------------------------------------------- fused attention
// QBLK=128, 8 waves (512 thr), 16 queries/wave. Key-split over blockIdx.z.
// Partials: Pacc bf16 [ks][bh][s][48], Plsum f32. Double-buffered K/V staging.
__global__ __launch_bounds__(512, 4) void attn(const short* __restrict__ Qt,
                                               const short* __restrict__ Kt,
                                               const short* __restrict__ Vc,
                                               const float* __restrict__ gbuf,
                                               unsigned short* __restrict__ Pacc,
                                               float* __restrict__ Plsum,
                                               int kchunk) {
  __shared__ short Kb[2][64][64];
  __shared__ short Vb[2][48][64];
  __shared__ short Pl[8][16][64];
  const int s0 = blockIdx.x * 128;
  const int bh = blockIdx.y;
  const int b = bh >> 2, h = bh & 3;
  const int ks = blockIdx.z;
  const int tid = threadIdx.x, w = tid >> 6, l = tid & 63;
  const int g16 = l >> 4, c16 = l & 15;
  const int sx = c16 & 7;
  const int tstart = ks * kchunk, tend = tstart + kchunk;

  const short* Kbase = Kt + (size_t)b * Tn * Cn + h * HD;
  const short* Vbase = Vc + ((size_t)(b * Cn + h * HD)) * Tn;

  // zero logical pad chunks (6,7) of both Kb buffers once (staging never touches)
  float4 z4;
  z4.x = z4.y = z4.z = z4.w = 0.f;
  if (tid < 256) {
    int bufz = tid >> 7, r = (tid >> 1) & 63, chp = 6 + (tid & 1);
    *(float4*)(&Kb[bufz][r][(chp ^ (r & 7)) * 8]) = z4;
  }
  // stage Q (128 rows) into Kb[0] and Kb[1] data chunks; read frags; reuse for K
  for (int idx = tid; idx < 768; idx += 512) {
    int row = idx / 6, ch = idx % 6;
    *(float4*)(&Kb[row >> 6][row & 63][(ch ^ (row & 7)) * 8]) =
        *(const float4*)(Qt + ((size_t)(b * Tn + s0 + row)) * Cn + h * HD + ch * 8);
  }
  __syncthreads();
  short8 qf[2];
  {
    int qr = (w & 3) * 16 + c16, qb_ = w >> 2;
    qf[0] = *(const short8*)(&Kb[qb_][qr][(g16 ^ sx) * 8]);
    qf[1] = *(const short8*)(&Kb[qb_][qr][((4 + g16) ^ sx) * 8]);
  }
  __syncthreads();

  // stage first tile into buf 0
  for (int idx = tid; idx < 768; idx += 512) {
    if (idx < 384) {
      int row = idx / 6, ch = idx % 6;
      *(float4*)(&Kb[0][row][(ch ^ (row & 7)) * 8]) =
          *(const float4*)(Kbase + ((size_t)(tstart + row)) * Cn + ch * 8);
    } else {
      int jj = idx - 384, row = jj >> 3, ch = jj & 7;
      *(float4*)(&Vb[0][row][(ch ^ (row & 7)) * 8]) =
          *(const float4*)(Vbase + (size_t)row * Tn + tstart + ch * 8);
    }
  }
  __syncthreads();

  // per-thread prefetch coordinates (item A: all threads; item B: tid<256)
  const bool aIsK = tid < 384;
  const int arow = aIsK ? tid / 6 : ((tid - 384) >> 3);
  const int ach = aIsK ? tid % 6 : ((tid - 384) & 7);
  const int dA = arow * 64 + ((ach ^ (arow & 7)) * 8);
  const bool hasB = tid < 256;
  const int brow = (128 + tid) >> 3, bch = (128 + tid) & 7;
  const int dB = brow * 64 + ((bch ^ (brow & 7)) * 8);

  const int s_lane = s0 + w * 16 + c16;
  const int sref = s0 + ((w >> 2) << 6);  // wave's diagonal-tile base
  const float g2 = gbuf[((size_t)(b * 4 + h)) * Tn + s_lane] * LOG2E;
  const float g16x = g2 * 16.0f;
  const float rb1 = g2, rb2 = g2 * 2.0f, rb3 = g2 * 3.0f;
  float base = g2 * (float)(tstart + g16 * 4 - s_lane);
  const float binc = g2 * 64.0f;
  float lsum = 0.f;
  f32x4 acc[3];
#pragma unroll
  for (int cs = 0; cs < 3; ++cs) acc[cs] = (f32x4){0.f, 0.f, 0.f, 0.f};

  int buf = 0;
  for (int t0 = tstart; t0 < tend; t0 += 64) {
    const int tn = t0 + 64;
    const bool hn = tn < tend;
    float4 r0, r1;
    if (hn) {  // issue next-tile global loads early; latency hides under compute
      r0 = aIsK ? *(const float4*)(Kbase + (size_t)(tn + arow) * Cn + ach * 8)
                : *(const float4*)(Vbase + (size_t)arow * Tn + tn + ach * 8);
      if (hasB) r1 = *(const float4*)(Vbase + (size_t)brow * Tn + tn + bch * 8);
    }
    const short* KbP = &Kb[buf][0][0];
    const short* VbP = &Vb[buf][0][0];

    // S = K_tile^T . Q
    f32x4 sacc[4];
#pragma unroll
    for (int m = 0; m < 4; ++m) sacc[m] = (f32x4){0.f, 0.f, 0.f, 0.f};
    __builtin_amdgcn_s_setprio(1);
#pragma unroll
    for (int kk = 0; kk < 2; ++kk)
#pragma unroll
      for (int m = 0; m < 4; ++m) {
        short8 af = *(const short8*)(KbP + (m * 16 + c16) * 64 + (((kk * 4 + g16) ^ sx) * 8));
        sacc[m] = mfma16(af, qf[kk], sacc[m]);
      }
    __builtin_amdgcn_s_setprio(0);

    // logits (log2 domain), 3-branch: whole tile left / right / diagonal
    if (t0 > sref) {  // all keys right of query: dist > 0
      float nbm = -base;
#pragma unroll
      for (int m = 0; m < 4; ++m) {
        float e0 = __builtin_amdgcn_exp2f(fmaf(sacc[m][0], QK_SCALE2, nbm));
        float e1 = __builtin_amdgcn_exp2f(fmaf(sacc[m][1], QK_SCALE2, nbm) - rb1);
        float e2 = __builtin_amdgcn_exp2f(fmaf(sacc[m][2], QK_SCALE2, nbm) - rb2);
        float e3 = __builtin_amdgcn_exp2f(fmaf(sacc[m][3], QK_SCALE2, nbm) - rb3);
        lsum += (e0 + e1) + (e2 + e3);
        unsigned long long u64v =
            ((unsigned long long)cvtpk(e2, e3) << 32) | (unsigned long long)cvtpk(e0, e1);
        *(unsigned long long*)(&Pl[w][c16][(((2 * m + (g16 >> 1)) ^ sx) * 8) + (g16 & 1) * 4]) =
            u64v;
        nbm -= g16x;
      }
    } else if (t0 < sref) {  // all keys left: dist < 0
      float pbm = base;
#pragma unroll
      for (int m = 0; m < 4; ++m) {
        float e0 = __builtin_amdgcn_exp2f(fmaf(sacc[m][0], QK_SCALE2, pbm));
        float e1 = __builtin_amdgcn_exp2f(fmaf(sacc[m][1], QK_SCALE2, pbm) + rb1);
        float e2 = __builtin_amdgcn_exp2f(fmaf(sacc[m][2], QK_SCALE2, pbm) + rb2);
        float e3 = __builtin_amdgcn_exp2f(fmaf(sacc[m][3], QK_SCALE2, pbm) + rb3);
        lsum += (e0 + e1) + (e2 + e3);
        unsigned long long u64v =
            ((unsigned long long)cvtpk(e2, e3) << 32) | (unsigned long long)cvtpk(e0, e1);
        *(unsigned long long*)(&Pl[w][c16][(((2 * m + (g16 >> 1)) ^ sx) * 8) + (g16 & 1) * 4]) =
            u64v;
        pbm += g16x;
      }
    } else {  // diagonal tile for this wave
      const float fbd = (float)(t0 + g16 * 4 - s_lane);
#pragma unroll
      for (int m = 0; m < 4; ++m) {
        float e[4];
#pragma unroll
        for (int r = 0; r < 4; ++r) {
          float d = fbd + (float)(16 * m + r);
          float ad = fabsf(d);
          float v = fmaf(-g2, ad, sacc[m][r] * QK_SCALE2);
          v = (ad < 0.5f) ? NEG100_LOG2 : v;
          e[r] = __builtin_amdgcn_exp2f(v);
        }
        lsum += (e[0] + e[1]) + (e[2] + e[3]);
        unsigned long long u64v = ((unsigned long long)cvtpk(e[2], e[3]) << 32) |
                                  (unsigned long long)cvtpk(e[0], e[1]);
        *(unsigned long long*)(&Pl[w][c16][(((2 * m + (g16 >> 1)) ^ sx) * 8) + (g16 & 1) * 4]) =
            u64v;
      }
    }
    base += binc;
    asm volatile("s_waitcnt lgkmcnt(0)" ::: "memory");

    // O += V_tile . P
    __builtin_amdgcn_s_setprio(1);
#pragma unroll
    for (int kk = 0; kk < 2; ++kk) {
      short8 pf = *(const short8*)(&Pl[w][c16][((kk * 4 + g16) ^ sx) * 8]);
#pragma unroll
      for (int cs = 0; cs < 3; ++cs) {
        short8 vf = *(const short8*)(VbP + (cs * 16 + c16) * 64 + (((kk * 4 + g16) ^ sx) * 8));
        acc[cs] = mfma16(vf, pf, acc[cs]);
      }
    }
    __builtin_amdgcn_s_setprio(0);
    __syncthreads();
    if (hn) {  // write prefetched tile into the other buffer
      short* KbN = &Kb[buf ^ 1][0][0];
      short* VbN = &Vb[buf ^ 1][0][0];
      if (aIsK)
        *(float4*)(KbN + dA) = r0;
      else
        *(float4*)(VbN + dA) = r0;
      if (hasB) *(float4*)(VbN + dB) = r1;
    }
    __syncthreads();
    buf ^= 1;
  }

  float lsum2 = lsum + __shfl_xor(lsum, 16);
  lsum2 += __shfl_xor(lsum2, 32);
  if (g16 == 0) Plsum[((size_t)(ks * 16 + bh)) * Tn + s_lane] = lsum2;

  // bounce acc -> LDS (bf16, reuse Kb: [128][24] u32 = 12 KB) then coalesced store
  unsigned int* Ob = (unsigned int*)&Kb[0][0][0];
  const int orow = w * 16 + c16;
#pragma unroll
  for (int cs = 0; cs < 3; ++cs) {
    Ob[orow * 24 + cs * 8 + g16 * 2 + 0] = cvtpk(acc[cs][0], acc[cs][1]);
    Ob[orow * 24 + cs * 8 + g16 * 2 + 1] = cvtpk(acc[cs][2], acc[cs][3]);
  }
  __syncthreads();
  float4* dst = (float4*)(Pacc + (((size_t)(ks * 16 + bh)) * Tn + s0) * 48);
  const float4* src = (const float4*)Ob;
  dst[tid] = src[tid];
  if (tid < 256) dst[tid + 512] = src[tid + 512];
}

// ---------------------------------------------------------------- combine partials
__global__ __launch_bounds__(256) void combine(const unsigned short* __restrict__ Pacc,
                                               const float* __restrict__ Plsum,
                                               short* __restrict__ Rt, int KS) {
  int idx = blockIdx.x * 256 + threadIdx.x;  // Bn*Tn*48
  int c4 = idx % 48;
  int rest = idx / 48;
  int s = rest & 2047;
  int b = rest >> 11;
  int c = c4 * 4;
  int h = c / 48;
  int cc = c - h * 48;
  size_t qb = ((size_t)(b * 4 + h)) * Tn + s;
  float a0 = 0.f, a1 = 0.f, a2 = 0.f, a3 = 0.f, lt = 0.f;
  for (int ks = 0; ks < KS; ++ks) {
    ushort4 v = *(const ushort4*)(Pacc + ((size_t)ks * 16 * Tn + qb) * 48 + cc);
    a0 += bf2f(v.x);
    a1 += bf2f(v.y);
    a2 += bf2f(v.z);
    a3 += bf2f(v.w);
    lt += Plsum[(size_t)ks * 16 * Tn + qb];
  }
  float inv = 1.f / lt;
  ushort4 pk;
  pk.x = f2bf(a0 * inv);
  pk.y = f2bf(a1 * inv);
  pk.z = f2bf(a2 * inv);
  pk.w = f2bf(a3 * inv);
  *(ushort4*)(Rt + ((size_t)(b * Tn + s)) * Cn + c) = pk;
}

// ---------------------------------------------------------------- final GEMM (t-tile 64)
__global__ __launch_bounds__(256) void gemm_out(const short* __restrict__ Awt,
                                                const float* __restrict__ bias,
                                                const short* __restrict__ Bsrc,
                                                float* __restrict__ O,
                                                const float* __restrict__ Xres) {
  constexpr int LDK = 200;
  __shared__ short As[64 * LDK];
  __shared__ short Bs[64 * LDK];
  int tt = blockIdx.x, nt = blockIdx.y, b = blockIdx.z;
  int n0 = nt * 64, t0 = tt * 64;
  int tid = threadIdx.x, w = tid >> 6, l = tid & 63;
  int g16 = l >> 4, c16 = l & 15;

  for (int idx = tid; idx < 3072; idx += 256) {
    if (idx < 1536) {
      int row = idx / 24, ch = idx % 24;
      *(float4*)(&As[row * LDK + ch * 8]) =
          *(const float4*)(Awt + ((size_t)(n0 + row)) * Cn + ch * 8);
    } else {
      int j = idx - 1536;
      int row = j / 24, ch = j % 24;
      *(float4*)(&Bs[row * LDK + ch * 8]) =
          *(const float4*)(Bsrc + ((size_t)(b * Tn + t0 + row)) * Cn + ch * 8);
    }
  }
  __syncthreads();

  f32x4 acc[4];
#pragma unroll
  for (int m = 0; m < 4; ++m) acc[m] = (f32x4){0.f, 0.f, 0.f, 0.f};

#pragma unroll
  for (int kk = 0; kk < 6; ++kk) {
    short8 bf = *(const short8*)(&Bs[(w * 16 + c16) * LDK + kk * 32 + g16 * 8]);
#pragma unroll
    for (int m = 0; m < 4; ++m) {
      short8 af = *(const short8*)(&As[(m * 16 + c16) * LDK + kk * 32 + g16 * 8]);
      acc[m] = mfma16(af, bf, acc[m]);
    }
  }

#pragma unroll
  for (int m = 0; m < 4; ++m) {
    int nrow = n0 + m * 16 + g16 * 4;
    int tcol = t0 + w * 16 + c16;
#pragma unroll
    for (int r = 0; r < 4; ++r) {
      size_t i = ((size_t)(b * Cn + nrow + r)) * Tn + tcol;
      O[i] = acc[m][r] + bias[nrow + r] + Xres[i];
    }
  }
}

// ---------------------------------------------------------------- launch
extern "C" void kernel_launch(void* const* d_in, const int* in_sizes, int n_in,
                              void* d_out, int out_size, void* d_ws, size_t ws_size,
                              hipStream_t stream) {
  const float* x = (const float*)d_in[0];
  const float* Wq = (const float*)d_in[1];
  const float* bq = (const float*)d_in[2];
  const float* Wk = (const float*)d_in[3];
  const float* bk = (const float*)d_in[4];
  const float* Wc = (const float*)d_in[5];
  const float* bc = (const float*)d_in[6];
  const float* Wd = (const float*)d_in[7];
  const float* bd = (const float*)d_in[8];
  const float* Wp = (const float*)d_in[9];
  const float* bp = (const float*)d_in[10];
  float* out = (float*)d_out;

  char* ws = (char*)d_ws;
  const size_t SZ = (size_t)Bn * Tn * Cn * sizeof(short);  // 3,145,728
  short* XTbf = (short*)(ws);
  short* Qt = (short*)(ws + SZ);
  short* Kt = (short*)(ws + 2 * SZ);
  short* Vc = (short*)(ws + 3 * SZ);
  short* Rt = (short*)(ws + 4 * SZ);
  short* WT = (short*)(ws + 5 * SZ);  // 4*192*192 shorts = 294912 B
  float* gbuf = (float*)(ws + 5 * SZ + 294912);
  char* pbase = ws + 5 * SZ + 294912 + 131072;

  const size_t base = 5 * SZ + 294912 + 131072;
  const size_t perks = (size_t)16 * Tn * 48 * 2 + (size_t)16 * Tn * 4;  // 3,276,800
  int KS = 2;
  if (ws_size && base + 2 * perks > ws_size) KS = 1;
  unsigned short* Pacc = (unsigned short*)pbase;
  float* Plsum = (float*)(pbase + (size_t)KS * 16 * Tn * 48 * 2);

  transpose_xw<<<dim3(Tn / 32, Cn / 32, Bn + 2), 256, 0, stream>>>(
      x, Wq, Wk, Wc, Wp, Wd, bd, XTbf, WT, gbuf);
  gemm_qkv<<<dim3(16, 9, Bn), 256, 0, stream>>>(WT, bq, bk, bc, XTbf, Qt, Kt, Vc);
  attn<<<dim3(Tn / 128, Bn * Hn, KS), 512, 0, stream>>>(Qt, Kt, Vc, gbuf, Pacc, Plsum,
                                                        Tn / KS);
  combine<<<dim3(Bn * Tn * 48 / 256), 256, 0, stream>>>(Pacc, Plsum, Rt, KS);
  gemm_out<<<dim3(32, 3, Bn), 256, 0, stream>>>(WT + 3 * 36864, bp, Rt, out, x);
}

// Round 13
// 75.912 us; speedup vs baseline: 1.0640x; 1.0640x over previous
//
#include <hip/hip_runtime.h>

typedef __attribute__((ext_vector_type(8))) short short8;
typedef __attribute__((ext_vector_type(4))) float f32x4;

constexpr int Bn = 4, Cn = 192, Tn = 2048, Hn = 4, HD = 48;
constexpr float LOG2E = 1.4426950408889634f;
constexpr float QK_SCALE2 = 0.14433756729740643f * 1.4426950408889634f;  // rsqrt(48)*log2e
constexpr float NEG100_LOG2 = -100.0f * 1.4426950408889634f;

__device__ inline unsigned short f2bf(float f) {
  unsigned int u = __builtin_bit_cast(unsigned int, f);
  return (unsigned short)((u + 0x7FFFu + ((u >> 16) & 1u)) >> 16);
}
__device__ inline float bf2f(unsigned short h) {
  unsigned int u = ((unsigned int)h) << 16;
  return __builtin_bit_cast(float, u);
}
__device__ inline f32x4 mfma16(short8 a, short8 b, f32x4 c) {
  return __builtin_amdgcn_mfma_f32_16x16x32_bf16(a, b, c, 0, 0, 0);
}
__device__ inline unsigned int cvtpk(float lo, float hi) {
  unsigned int r;
  asm("v_cvt_pk_bf16_f32 %0, %1, %2" : "=v"(r) : "v"(lo), "v"(hi));
  return r;
}

// ---------------------------------------------------------------- transpose x + weights
// z<Bn : x[b][c][t] f32 -> XT[b][t][c] bf16 (b=z)
// z==Bn: W[k][n] f32 -> WT[j][n][k] bf16 (j=0..3: Wq,Wk,Wc,Wp), 144 tile-jobs
__global__ __launch_bounds__(256) void transpose_xw(const float* __restrict__ x,
                                                    const float* __restrict__ Wq,
                                                    const float* __restrict__ Wk,
                                                    const float* __restrict__ Wc,
                                                    const float* __restrict__ Wp,
                                                    short* __restrict__ xt,
                                                    short* __restrict__ WT) {
  __shared__ short tile[32][40];
  int tid = threadIdx.x;
  int row = tid >> 3, q = tid & 7;
  int z = blockIdx.z;
  if (z < Bn) {
    int t0 = blockIdx.x * 32, c0 = blockIdx.y * 32, b = z;
    float4 v = *(const float4*)(x + ((size_t)(b * Cn + c0 + row)) * Tn + t0 + q * 4);
    tile[row][q * 4 + 0] = (short)f2bf(v.x);
    tile[row][q * 4 + 1] = (short)f2bf(v.y);
    tile[row][q * 4 + 2] = (short)f2bf(v.z);
    tile[row][q * 4 + 3] = (short)f2bf(v.w);
    __syncthreads();
    ushort4 pk;
    pk.x = (unsigned short)tile[q * 4 + 0][row];
    pk.y = (unsigned short)tile[q * 4 + 1][row];
    pk.z = (unsigned short)tile[q * 4 + 2][row];
    pk.w = (unsigned short)tile[q * 4 + 3][row];
    *(ushort4*)(xt + ((size_t)(b * Tn + t0 + row)) * Cn + c0 + q * 4) = pk;
  } else {
    int idx = blockIdx.y * 64 + blockIdx.x;  // 384 slots, need 144
    if (idx >= 144) return;
    int j = idx / 36, t = idx - j * 36;
    int k0 = (t / 6) * 32, n0 = (t % 6) * 32;
    const float* W = (j == 0) ? Wq : (j == 1) ? Wk : (j == 2) ? Wc : Wp;
    float4 v = *(const float4*)(W + (size_t)(k0 + row) * Cn + n0 + q * 4);
    tile[row][q * 4 + 0] = (short)f2bf(v.x);
    tile[row][q * 4 + 1] = (short)f2bf(v.y);
    tile[row][q * 4 + 2] = (short)f2bf(v.z);
    tile[row][q * 4 + 3] = (short)f2bf(v.w);
    __syncthreads();
    ushort4 pk;
    pk.x = (unsigned short)tile[q * 4 + 0][row];
    pk.y = (unsigned short)tile[q * 4 + 1][row];
    pk.z = (unsigned short)tile[q * 4 + 2][row];
    pk.w = (unsigned short)tile[q * 4 + 3][row];
    *(ushort4*)(WT + ((size_t)(j * Cn + n0 + row)) * Cn + k0 + q * 4) = pk;
  }
}

// ---------------------------------------------------------------- fused QKV GEMM
// nt 0..8 over concatenated [WqT;WkT;WcT] rows; Q,K -> t-major bf16; V -> c-major
__global__ __launch_bounds__(256) void gemm_qkv(const short* __restrict__ WT,
                                                const float* __restrict__ bq,
                                                const float* __restrict__ bk,
                                                const float* __restrict__ bc,
                                                const short* __restrict__ Bsrc,
                                                short* __restrict__ Qt,
                                                short* __restrict__ Kt,
                                                short* __restrict__ Vc) {
  constexpr int LDK = 200;
  __shared__ short As[64 * LDK];
  __shared__ short Bs[128 * LDK];
  int tt = blockIdx.x, nt = blockIdx.y, b = blockIdx.z;
  int j = nt / 3;              // 0=Q 1=K 2=V
  int ln0 = (nt - j * 3) * 64; // row within its matrix
  int n0g = nt * 64;           // row in concatenated WT
  int t0 = tt * 128;
  const float* bias = (j == 0) ? bq : (j == 1) ? bk : bc;
  int tid = threadIdx.x, w = tid >> 6, l = tid & 63;
  int g16 = l >> 4, c16 = l & 15;

  for (int idx = tid; idx < 4608; idx += 256) {
    if (idx < 1536) {
      int row = idx / 24, ch = idx % 24;
      *(float4*)(&As[row * LDK + ch * 8]) =
          *(const float4*)(WT + ((size_t)(n0g + row)) * Cn + ch * 8);
    } else {
      int jj = idx - 1536;
      int row = jj / 24, ch = jj % 24;
      *(float4*)(&Bs[row * LDK + ch * 8]) =
          *(const float4*)(Bsrc + ((size_t)(b * Tn + t0 + row)) * Cn + ch * 8);
    }
  }
  __syncthreads();

  f32x4 acc[4][2];
#pragma unroll
  for (int m = 0; m < 4; ++m)
#pragma unroll
    for (int n = 0; n < 2; ++n) acc[m][n] = (f32x4){0.f, 0.f, 0.f, 0.f};

#pragma unroll
  for (int kk = 0; kk < 6; ++kk) {
    short8 af[4], bf[2];
#pragma unroll
    for (int m = 0; m < 4; ++m)
      af[m] = *(const short8*)(&As[(m * 16 + c16) * LDK + kk * 32 + g16 * 8]);
#pragma unroll
    for (int n = 0; n < 2; ++n)
      bf[n] = *(const short8*)(&Bs[(w * 32 + n * 16 + c16) * LDK + kk * 32 + g16 * 8]);
#pragma unroll
    for (int m = 0; m < 4; ++m)
#pragma unroll
      for (int n = 0; n < 2; ++n) acc[m][n] = mfma16(af[m], bf[n], acc[m][n]);
  }

#pragma unroll
  for (int m = 0; m < 4; ++m)
#pragma unroll
    for (int n = 0; n < 2; ++n) {
      int nrow = ln0 + m * 16 + g16 * 4;
      int tcol = t0 + w * 32 + n * 16 + c16;
      if (j == 2) {
#pragma unroll
        for (int r = 0; r < 4; ++r)
          Vc[((size_t)(b * Cn + nrow + r)) * Tn + tcol] =
              (short)f2bf(acc[m][n][r] + bias[nrow + r]);
      } else {
        short* O = j ? Kt : Qt;
        ushort4 pk;
        pk.x = f2bf(acc[m][n][0] + bias[nrow + 0]);
        pk.y = f2bf(acc[m][n][1] + bias[nrow + 1]);
        pk.z = f2bf(acc[m][n][2] + bias[nrow + 2]);
        pk.w = f2bf(acc[m][n][3] + bias[nrow + 3]);
        *(ushort4*)(O + ((size_t)(b * Tn + tcol)) * Cn + nrow) = pk;
      }
    }
}

// ---------------------------------------------------------------- decay scalar
// g[b][h][t] = 0.25 * sum_f (f+1)*sigmoid( (xt@Wd + bd)[b,t,h*4+f] ); 8-way k-split
__global__ __launch_bounds__(256) void decay_g(const short* __restrict__ xt,
                                               const float* __restrict__ Wd,
                                               const float* __restrict__ bd,
                                               float* __restrict__ gout) {
  int idx = blockIdx.x * 256 + threadIdx.x;  // Bn*Tn*8 = 65536 total
  int kq = idx & 7;
  int t = (idx >> 3) & 2047;
  int b = idx >> 14;
  const short* xr = xt + ((size_t)(b * Tn + t)) * Cn + kq * 24;
  const float* wr = Wd + kq * 24 * 16;
  float d[16];
#pragma unroll
  for (int n = 0; n < 16; ++n) d[n] = 0.f;
#pragma unroll
  for (int k = 0; k < 24; k += 8) {
    short8 xv8 = *(const short8*)(xr + k);
#pragma unroll
    for (int jj = 0; jj < 8; ++jj) {
      float xv = bf2f((unsigned short)xv8[jj]);
      const float* wrow = wr + (k + jj) * 16;
#pragma unroll
      for (int n = 0; n < 16; ++n) d[n] = fmaf(xv, wrow[n], d[n]);
    }
  }
#pragma unroll
  for (int n = 0; n < 16; ++n) {
    d[n] += __shfl_xor(d[n], 1);
    d[n] += __shfl_xor(d[n], 2);
    d[n] += __shfl_xor(d[n], 4);
  }
  if (kq == 0) {
#pragma unroll
    for (int h = 0; h < 4; ++h) {
      float gsum = 0.f;
#pragma unroll
      for (int f = 0; f < 4; ++f) {
        float s = 1.f / (1.f + __expf(-(d[h * 4 + f] + bd[h * 4 + f])));
        gsum += (float)(f + 1) * s;
      }
      gout[((size_t)(b * 4 + h)) * Tn + t] = 0.25f * gsum;
    }
  }
}

// ---------------------------------------------------------------- fused attention
// QBLK=128, 8 waves (512 thr), 16 queries/wave. Key-split over blockIdx.z.
// Partials: Pacc bf16 [ks][bh][s][48], Plsum f32. Double-buffered K/V staging,
// single barrier per tile (writes target the non-read buffer; see proof in R12 notes).
__global__ __launch_bounds__(512, 4) void attn(const short* __restrict__ Qt,
                                               const short* __restrict__ Kt,
                                               const short* __restrict__ Vc,
                                               const float* __restrict__ gbuf,
                                               unsigned short* __restrict__ Pacc,
                                               float* __restrict__ Plsum,
                                               int kchunk) {
  __shared__ short Kb[2][64][64];
  __shared__ short Vb[2][48][64];
  __shared__ short Pl[8][16][64];
  const int s0 = blockIdx.x * 128;
  const int bh = blockIdx.y;
  const int b = bh >> 2, h = bh & 3;
  const int ks = blockIdx.z;
  const int tid = threadIdx.x, w = tid >> 6, l = tid & 63;
  const int g16 = l >> 4, c16 = l & 15;
  const int sx = c16 & 7;
  const int tstart = ks * kchunk, tend = tstart + kchunk;

  const short* Kbase = Kt + (size_t)b * Tn * Cn + h * HD;
  const short* Vbase = Vc + ((size_t)(b * Cn + h * HD)) * Tn;

  // zero logical pad chunks (6,7) of both Kb buffers once (staging never touches)
  float4 z4;
  z4.x = z4.y = z4.z = z4.w = 0.f;
  if (tid < 256) {
    int bufz = tid >> 7, r = (tid >> 1) & 63, chp = 6 + (tid & 1);
    *(float4*)(&Kb[bufz][r][(chp ^ (r & 7)) * 8]) = z4;
  }
  // stage Q (128 rows) into Kb[0] and Kb[1] data chunks; read frags; reuse for K
  for (int idx = tid; idx < 768; idx += 512) {
    int row = idx / 6, ch = idx % 6;
    *(float4*)(&Kb[row >> 6][row & 63][(ch ^ (row & 7)) * 8]) =
        *(const float4*)(Qt + ((size_t)(b * Tn + s0 + row)) * Cn + h * HD + ch * 8);
  }
  __syncthreads();
  short8 qf[2];
  {
    int qr = (w & 3) * 16 + c16, qb_ = w >> 2;
    qf[0] = *(const short8*)(&Kb[qb_][qr][(g16 ^ sx) * 8]);
    qf[1] = *(const short8*)(&Kb[qb_][qr][((4 + g16) ^ sx) * 8]);
  }
  __syncthreads();

  // stage first tile into buf 0
  for (int idx = tid; idx < 768; idx += 512) {
    if (idx < 384) {
      int row = idx / 6, ch = idx % 6;
      *(float4*)(&Kb[0][row][(ch ^ (row & 7)) * 8]) =
          *(const float4*)(Kbase + ((size_t)(tstart + row)) * Cn + ch * 8);
    } else {
      int jj = idx - 384, row = jj >> 3, ch = jj & 7;
      *(float4*)(&Vb[0][row][(ch ^ (row & 7)) * 8]) =
          *(const float4*)(Vbase + (size_t)row * Tn + tstart + ch * 8);
    }
  }
  __syncthreads();

  // per-thread prefetch coordinates (item A: all threads; item B: tid<256)
  const bool aIsK = tid < 384;
  const int arow = aIsK ? tid / 6 : ((tid - 384) >> 3);
  const int ach = aIsK ? tid % 6 : ((tid - 384) & 7);
  const int dA = arow * 64 + ((ach ^ (arow & 7)) * 8);
  const bool hasB = tid < 256;
  const int brow = (128 + tid) >> 3, bch = (128 + tid) & 7;
  const int dB = brow * 64 + ((bch ^ (brow & 7)) * 8);

  const int s_lane = s0 + w * 16 + c16;
  const int sref = s0 + ((w >> 2) << 6);  // wave's diagonal-tile base
  const float g2 = gbuf[((size_t)(b * 4 + h)) * Tn + s_lane] * LOG2E;
  const float g16x = g2 * 16.0f;
  const float rb1 = g2, rb2 = g2 * 2.0f, rb3 = g2 * 3.0f;
  float base = g2 * (float)(tstart + g16 * 4 - s_lane);
  const float binc = g2 * 64.0f;
  float lsum = 0.f;
  f32x4 acc[3];
#pragma unroll
  for (int cs = 0; cs < 3; ++cs) acc[cs] = (f32x4){0.f, 0.f, 0.f, 0.f};

  int buf = 0;
  for (int t0 = tstart; t0 < tend; t0 += 64) {
    const int tn = t0 + 64;
    const bool hn = tn < tend;
    float4 r0, r1;
    if (hn) {  // issue next-tile global loads early; latency hides under compute
      r0 = aIsK ? *(const float4*)(Kbase + (size_t)(tn + arow) * Cn + ach * 8)
                : *(const float4*)(Vbase + (size_t)arow * Tn + tn + ach * 8);
      if (hasB) r1 = *(const float4*)(Vbase + (size_t)brow * Tn + tn + bch * 8);
    }
    const short* KbP = &Kb[buf][0][0];
    const short* VbP = &Vb[buf][0][0];

    // S = K_tile^T . Q
    f32x4 sacc[4];
#pragma unroll
    for (int m = 0; m < 4; ++m) sacc[m] = (f32x4){0.f, 0.f, 0.f, 0.f};
    __builtin_amdgcn_s_setprio(1);
#pragma unroll
    for (int kk = 0; kk < 2; ++kk)
#pragma unroll
      for (int m = 0; m < 4; ++m) {
        short8 af = *(const short8*)(KbP + (m * 16 + c16) * 64 + (((kk * 4 + g16) ^ sx) * 8));
        sacc[m] = mfma16(af, qf[kk], sacc[m]);
      }
    __builtin_amdgcn_s_setprio(0);

    // logits (log2 domain), 3-branch: whole tile left / right / diagonal
    if (t0 > sref) {  // all keys right of query: dist > 0
      float nbm = -base;
#pragma unroll
      for (int m = 0; m < 4; ++m) {
        float e0 = __builtin_amdgcn_exp2f(fmaf(sacc[m][0], QK_SCALE2, nbm));
        float e1 = __builtin_amdgcn_exp2f(fmaf(sacc[m][1], QK_SCALE2, nbm) - rb1);
        float e2 = __builtin_amdgcn_exp2f(fmaf(sacc[m][2], QK_SCALE2, nbm) - rb2);
        float e3 = __builtin_amdgcn_exp2f(fmaf(sacc[m][3], QK_SCALE2, nbm) - rb3);
        lsum += (e0 + e1) + (e2 + e3);
        unsigned long long u64v =
            ((unsigned long long)cvtpk(e2, e3) << 32) | (unsigned long long)cvtpk(e0, e1);
        *(unsigned long long*)(&Pl[w][c16][(((2 * m + (g16 >> 1)) ^ sx) * 8) + (g16 & 1) * 4]) =
            u64v;
        nbm -= g16x;
      }
    } else if (t0 < sref) {  // all keys left: dist < 0
      float pbm = base;
#pragma unroll
      for (int m = 0; m < 4; ++m) {
        float e0 = __builtin_amdgcn_exp2f(fmaf(sacc[m][0], QK_SCALE2, pbm));
        float e1 = __builtin_amdgcn_exp2f(fmaf(sacc[m][1], QK_SCALE2, pbm) + rb1);
        float e2 = __builtin_amdgcn_exp2f(fmaf(sacc[m][2], QK_SCALE2, pbm) + rb2);
        float e3 = __builtin_amdgcn_exp2f(fmaf(sacc[m][3], QK_SCALE2, pbm) + rb3);
        lsum += (e0 + e1) + (e2 + e3);
        unsigned long long u64v =
            ((unsigned long long)cvtpk(e2, e3) << 32) | (unsigned long long)cvtpk(e0, e1);
        *(unsigned long long*)(&Pl[w][c16][(((2 * m + (g16 >> 1)) ^ sx) * 8) + (g16 & 1) * 4]) =
            u64v;
        pbm += g16x;
      }
    } else {  // diagonal tile for this wave
      const float fbd = (float)(t0 + g16 * 4 - s_lane);
#pragma unroll
      for (int m = 0; m < 4; ++m) {
        float e[4];
#pragma unroll
        for (int r = 0; r < 4; ++r) {
          float d = fbd + (float)(16 * m + r);
          float ad = fabsf(d);
          float v = fmaf(-g2, ad, sacc[m][r] * QK_SCALE2);
          v = (ad < 0.5f) ? NEG100_LOG2 : v;
          e[r] = __builtin_amdgcn_exp2f(v);
        }
        lsum += (e[0] + e[1]) + (e[2] + e[3]);
        unsigned long long u64v = ((unsigned long long)cvtpk(e[2], e[3]) << 32) |
                                  (unsigned long long)cvtpk(e[0], e[1]);
        *(unsigned long long*)(&Pl[w][c16][(((2 * m + (g16 >> 1)) ^ sx) * 8) + (g16 & 1) * 4]) =
            u64v;
      }
    }
    base += binc;
    asm volatile("s_waitcnt lgkmcnt(0)" ::: "memory");

    // O += V_tile . P
    __builtin_amdgcn_s_setprio(1);
#pragma unroll
    for (int kk = 0; kk < 2; ++kk) {
      short8 pf = *(const short8*)(&Pl[w][c16][((kk * 4 + g16) ^ sx) * 8]);
#pragma unroll
      for (int cs = 0; cs < 3; ++cs) {
        short8 vf = *(const short8*)(VbP + (cs * 16 + c16) * 64 + (((kk * 4 + g16) ^ sx) * 8));
        acc[cs] = mfma16(vf, pf, acc[cs]);
      }
    }
    __builtin_amdgcn_s_setprio(0);
    // write prefetched tile into the non-read buffer; all waves are inside this
    // iteration (prev end-barrier passed), and this iteration reads only buf,
    // so writing buf^1 is race-free without a preceding barrier.
    if (hn) {
      short* KbN = &Kb[buf ^ 1][0][0];
      short* VbN = &Vb[buf ^ 1][0][0];
      if (aIsK)
        *(float4*)(KbN + dA) = r0;
      else
        *(float4*)(VbN + dA) = r0;
      if (hasB) *(float4*)(VbN + dB) = r1;
    }
    __syncthreads();
    buf ^= 1;
  }

  float lsum2 = lsum + __shfl_xor(lsum, 16);
  lsum2 += __shfl_xor(lsum2, 32);
  if (g16 == 0) Plsum[((size_t)(ks * 16 + bh)) * Tn + s_lane] = lsum2;

  // bounce acc -> LDS (bf16, reuse Kb: [128][24] u32 = 12 KB) then coalesced store
  unsigned int* Ob = (unsigned int*)&Kb[0][0][0];
  const int orow = w * 16 + c16;
#pragma unroll
  for (int cs = 0; cs < 3; ++cs) {
    Ob[orow * 24 + cs * 8 + g16 * 2 + 0] = cvtpk(acc[cs][0], acc[cs][1]);
    Ob[orow * 24 + cs * 8 + g16 * 2 + 1] = cvtpk(acc[cs][2], acc[cs][3]);
  }
  __syncthreads();
  float4* dst = (float4*)(Pacc + (((size_t)(ks * 16 + bh)) * Tn + s0) * 48);
  const float4* src = (const float4*)Ob;
  dst[tid] = src[tid];
  if (tid < 256) dst[tid + 512] = src[tid + 512];
}

// ---------------------------------------------------------------- combine partials
__global__ __launch_bounds__(256) void combine(const unsigned short* __restrict__ Pacc,
                                               const float* __restrict__ Plsum,
                                               short* __restrict__ Rt, int KS) {
  int idx = blockIdx.x * 256 + threadIdx.x;  // Bn*Tn*48
  int c4 = idx % 48;
  int rest = idx / 48;
  int s = rest & 2047;
  int b = rest >> 11;
  int c = c4 * 4;
  int h = c / 48;
  int cc = c - h * 48;
  size_t qb = ((size_t)(b * 4 + h)) * Tn + s;
  float a0 = 0.f, a1 = 0.f, a2 = 0.f, a3 = 0.f, lt = 0.f;
  for (int ks = 0; ks < KS; ++ks) {
    ushort4 v = *(const ushort4*)(Pacc + ((size_t)ks * 16 * Tn + qb) * 48 + cc);
    a0 += bf2f(v.x);
    a1 += bf2f(v.y);
    a2 += bf2f(v.z);
    a3 += bf2f(v.w);
    lt += Plsum[(size_t)ks * 16 * Tn + qb];
  }
  float inv = 1.f / lt;
  ushort4 pk;
  pk.x = f2bf(a0 * inv);
  pk.y = f2bf(a1 * inv);
  pk.z = f2bf(a2 * inv);
  pk.w = f2bf(a3 * inv);
  *(ushort4*)(Rt + ((size_t)(b * Tn + s)) * Cn + c) = pk;
}

// ---------------------------------------------------------------- final GEMM (t-tile 64)
__global__ __launch_bounds__(256) void gemm_out(const short* __restrict__ Awt,
                                                const float* __restrict__ bias,
                                                const short* __restrict__ Bsrc,
                                                float* __restrict__ O,
                                                const float* __restrict__ Xres) {
  constexpr int LDK = 200;
  __shared__ short As[64 * LDK];
  __shared__ short Bs[64 * LDK];
  int tt = blockIdx.x, nt = blockIdx.y, b = blockIdx.z;
  int n0 = nt * 64, t0 = tt * 64;
  int tid = threadIdx.x, w = tid >> 6, l = tid & 63;
  int g16 = l >> 4, c16 = l & 15;

  for (int idx = tid; idx < 3072; idx += 256) {
    if (idx < 1536) {
      int row = idx / 24, ch = idx % 24;
      *(float4*)(&As[row * LDK + ch * 8]) =
          *(const float4*)(Awt + ((size_t)(n0 + row)) * Cn + ch * 8);
    } else {
      int j = idx - 1536;
      int row = j / 24, ch = j % 24;
      *(float4*)(&Bs[row * LDK + ch * 8]) =
          *(const float4*)(Bsrc + ((size_t)(b * Tn + t0 + row)) * Cn + ch * 8);
    }
  }
  __syncthreads();

  f32x4 acc[4];
#pragma unroll
  for (int m = 0; m < 4; ++m) acc[m] = (f32x4){0.f, 0.f, 0.f, 0.f};

#pragma unroll
  for (int kk = 0; kk < 6; ++kk) {
    short8 bf = *(const short8*)(&Bs[(w * 16 + c16) * LDK + kk * 32 + g16 * 8]);
#pragma unroll
    for (int m = 0; m < 4; ++m) {
      short8 af = *(const short8*)(&As[(m * 16 + c16) * LDK + kk * 32 + g16 * 8]);
      acc[m] = mfma16(af, bf, acc[m]);
    }
  }

#pragma unroll
  for (int m = 0; m < 4; ++m) {
    int nrow = n0 + m * 16 + g16 * 4;
    int tcol = t0 + w * 16 + c16;
#pragma unroll
    for (int r = 0; r < 4; ++r) {
      size_t i = ((size_t)(b * Cn + nrow + r)) * Tn + tcol;
      O[i] = acc[m][r] + bias[nrow + r] + Xres[i];
    }
  }
}

// ---------------------------------------------------------------- launch
extern "C" void kernel_launch(void* const* d_in, const int* in_sizes, int n_in,
                              void* d_out, int out_size, void* d_ws, size_t ws_size,
                              hipStream_t stream) {
  const float* x = (const float*)d_in[0];
  const float* Wq = (const float*)d_in[1];
  const float* bq = (const float*)d_in[2];
  const float* Wk = (const float*)d_in[3];
  const float* bk = (const float*)d_in[4];
  const float* Wc = (const float*)d_in[5];
  const float* bc = (const float*)d_in[6];
  const float* Wd = (const float*)d_in[7];
  const float* bd = (const float*)d_in[8];
  const float* Wp = (const float*)d_in[9];
  const float* bp = (const float*)d_in[10];
  float* out = (float*)d_out;

  char* ws = (char*)d_ws;
  const size_t SZ = (size_t)Bn * Tn * Cn * sizeof(short);  // 3,145,728
  short* XTbf = (short*)(ws);
  short* Qt = (short*)(ws + SZ);
  short* Kt = (short*)(ws + 2 * SZ);
  short* Vc = (short*)(ws + 3 * SZ);
  short* Rt = (short*)(ws + 4 * SZ);
  short* WT = (short*)(ws + 5 * SZ);  // 4*192*192 shorts = 294912 B
  float* gbuf = (float*)(ws + 5 * SZ + 294912);
  char* pbase = ws + 5 * SZ + 294912 + 131072;

  const size_t base = 5 * SZ + 294912 + 131072;
  const size_t perks = (size_t)16 * Tn * 48 * 2 + (size_t)16 * Tn * 4;  // 3,276,800
  int KS = 2;
  if (ws_size && base + 2 * perks > ws_size) KS = 1;
  unsigned short* Pacc = (unsigned short*)pbase;
  float* Plsum = (float*)(pbase + (size_t)KS * 16 * Tn * 48 * 2);

  transpose_xw<<<dim3(Tn / 32, Cn / 32, Bn + 1), 256, 0, stream>>>(x, Wq, Wk, Wc, Wp,
                                                                   XTbf, WT);
  gemm_qkv<<<dim3(16, 9, Bn), 256, 0, stream>>>(WT, bq, bk, bc, XTbf, Qt, Kt, Vc);
  decay_g<<<dim3(256), 256, 0, stream>>>(XTbf, Wd, bd, gbuf);
  attn<<<dim3(Tn / 128, Bn * Hn, KS), 512, 0, stream>>>(Qt, Kt, Vc, gbuf, Pacc, Plsum,
                                                        Tn / KS);
  combine<<<dim3(Bn * Tn * 48 / 256), 256, 0, stream>>>(Pacc, Plsum, Rt, KS);
  gemm_out<<<dim3(32, 3, Bn), 256, 0, stream>>>(WT + 3 * 36864, bp, Rt, out, x);
}